// Round 1
// baseline (22.102 us; speedup 1.0000x reference)
//
#include <hip/hip_runtime.h>
#include <math.h>

namespace {

constexpr int   kB      = 8192;
constexpr int   kD      = 256;      // dims; 64 lanes * float4
constexpr float kMargin = 1.0f;
constexpr float kEps    = 1e-12f;

__device__ inline float4 ld4(const float* __restrict__ tab, int row, int lane) {
    return reinterpret_cast<const float4*>(tab + (size_t)row * kD)[lane];
}

__device__ inline float dot4(const float4& a, const float4& b) {
    return a.x * b.x + a.y * b.y + a.z * b.z + a.w * b.w;
}

// a + b * s
__device__ inline float4 fma4(const float4& a, const float4& b, float s) {
    float4 r;
    r.x = fmaf(b.x, s, a.x);
    r.y = fmaf(b.y, s, a.y);
    r.z = fmaf(b.z, s, a.z);
    r.w = fmaf(b.w, s, a.w);
    return r;
}

__global__ __launch_bounds__(256) void transd_kernel(
    const int* __restrict__ X, const int* __restrict__ Y,
    const float* __restrict__ ent_emb, const float* __restrict__ rel_emb,
    const float* __restrict__ ent_proj, const float* __restrict__ rel_proj,
    float* __restrict__ out)
{
    const int gtid = blockIdx.x * blockDim.x + threadIdx.x;
    const int b    = gtid >> 6;
    const int lane = gtid & 63;
    if (b >= kB) return;

    // triple indices (pos from X, neg from Y); layout [B,3] row-major
    const int ph = X[b * 3 + 0], pr = X[b * 3 + 1], pt = X[b * 3 + 2];
    const int nh = Y[b * 3 + 0], nr = Y[b * 3 + 1], nt = Y[b * 3 + 2];

    // Issue all 12 gathers early for memory-level parallelism.
    float4 Ph  = ld4(ent_emb,  ph, lane);
    float4 Pr  = ld4(rel_emb,  pr, lane);
    float4 Pt  = ld4(ent_emb,  pt, lane);
    float4 Php = ld4(ent_proj, ph, lane);
    float4 Prp = ld4(rel_proj, pr, lane);
    float4 Ptp = ld4(ent_proj, pt, lane);
    float4 Nh  = ld4(ent_emb,  nh, lane);
    float4 Nr  = ld4(rel_emb,  nr, lane);
    float4 Nt  = ld4(ent_emb,  nt, lane);
    float4 Nhp = ld4(ent_proj, nh, lane);
    float4 Nrp = ld4(rel_proj, nr, lane);
    float4 Ntp = ld4(ent_proj, nt, lane);

    // projection dot products: dot(h_p, h), dot(t_p, t) for pos & neg
    float dPh = dot4(Php, Ph), dPt = dot4(Ptp, Pt);
    float dNh = dot4(Nhp, Nh), dNt = dot4(Ntp, Nt);
    #pragma unroll
    for (int off = 1; off < 64; off <<= 1) {
        dPh += __shfl_xor(dPh, off, 64);
        dPt += __shfl_xor(dPt, off, 64);
        dNh += __shfl_xor(dNh, off, 64);
        dNt += __shfl_xor(dNt, off, 64);
    }

    // h_ = h + r_p * dot(h_p, h); t_ = t + r_p * dot(t_p, t)
    float4 Ph_ = fma4(Ph, Prp, dPh);
    float4 Pt_ = fma4(Pt, Prp, dPt);
    float4 Nh_ = fma4(Nh, Nrp, dNh);
    float4 Nt_ = fma4(Nt, Nrp, dNt);

    // squared norms of h_, r, t_ for pos & neg (6 simultaneous reductions)
    float qPh = dot4(Ph_, Ph_), qPr = dot4(Pr, Pr), qPt = dot4(Pt_, Pt_);
    float qNh = dot4(Nh_, Nh_), qNr = dot4(Nr, Nr), qNt = dot4(Nt_, Nt_);
    #pragma unroll
    for (int off = 1; off < 64; off <<= 1) {
        qPh += __shfl_xor(qPh, off, 64);
        qPr += __shfl_xor(qPr, off, 64);
        qPt += __shfl_xor(qPt, off, 64);
        qNh += __shfl_xor(qNh, off, 64);
        qNr += __shfl_xor(qNr, off, 64);
        qNt += __shfl_xor(qNt, off, 64);
    }

    const float iPh = 1.0f / fmaxf(sqrtf(qPh), kEps);
    const float iPr = 1.0f / fmaxf(sqrtf(qPr), kEps);
    const float iPt = 1.0f / fmaxf(sqrtf(qPt), kEps);
    const float iNh = 1.0f / fmaxf(sqrtf(qNh), kEps);
    const float iNr = 1.0f / fmaxf(sqrtf(qNr), kEps);
    const float iNt = 1.0f / fmaxf(sqrtf(qNt), kEps);

    // s = normalize(h_) + normalize(r) - normalize(t_), per component
    float4 Ps, Ns;
    Ps.x = Ph_.x * iPh + Pr.x * iPr - Pt_.x * iPt;
    Ps.y = Ph_.y * iPh + Pr.y * iPr - Pt_.y * iPt;
    Ps.z = Ph_.z * iPh + Pr.z * iPr - Pt_.z * iPt;
    Ps.w = Ph_.w * iPh + Pr.w * iPr - Pt_.w * iPt;
    Ns.x = Nh_.x * iNh + Nr.x * iNr - Nt_.x * iNt;
    Ns.y = Nh_.y * iNh + Nr.y * iNr - Nt_.y * iNt;
    Ns.z = Nh_.z * iNh + Nr.z * iNr - Nt_.z * iNt;
    Ns.w = Nh_.w * iNh + Nr.w * iNr - Nt_.w * iNt;

    float sP = dot4(Ps, Ps);
    float sN = dot4(Ns, Ns);
    #pragma unroll
    for (int off = 1; off < 64; off <<= 1) {
        sP += __shfl_xor(sP, off, 64);
        sN += __shfl_xor(sN, off, 64);
    }

    if (lane == 0) {
        out[b] = fmaxf(sqrtf(sP) - sqrtf(sN) + kMargin, 0.0f);
    }
}

} // namespace

extern "C" void kernel_launch(void* const* d_in, const int* in_sizes, int n_in,
                              void* d_out, int out_size, void* d_ws, size_t ws_size,
                              hipStream_t stream) {
    const int*   X        = (const int*)  d_in[0];
    const int*   Y        = (const int*)  d_in[1];
    const float* ent_emb  = (const float*)d_in[2];
    const float* rel_emb  = (const float*)d_in[3];
    const float* ent_proj = (const float*)d_in[4];
    const float* rel_proj = (const float*)d_in[5];
    float*       out      = (float*)d_out;

    // one 64-lane wave per batch row; 4 waves per 256-thread block
    const int threads = 256;
    const int blocks  = (kB * 64) / threads;   // 2048
    transd_kernel<<<blocks, threads, 0, stream>>>(
        X, Y, ent_emb, rel_emb, ent_proj, rel_proj, out);
}

// Round 5
// 21.585 us; speedup vs baseline: 1.0239x; 1.0239x over previous
//
#include <hip/hip_runtime.h>
#include <math.h>

namespace {

constexpr int   kB      = 8192;
constexpr int   kD      = 256;      // dims; 64 lanes * float4
constexpr float kMargin = 1.0f;
constexpr float kEps    = 1e-12f;

__device__ inline float4 ld4(const float* __restrict__ tab, int row, int lane) {
    return reinterpret_cast<const float4*>(tab + (size_t)row * kD)[lane];
}

__device__ inline float dot4(const float4& a, const float4& b) {
    return a.x * b.x + a.y * b.y + a.z * b.z + a.w * b.w;
}

// a + b * s
__device__ inline float4 fma4(const float4& a, const float4& b, float s) {
    float4 r;
    r.x = fmaf(b.x, s, a.x);
    r.y = fmaf(b.y, s, a.y);
    r.z = fmaf(b.z, s, a.z);
    r.w = fmaf(b.w, s, a.w);
    return r;
}

// Phase-split version: one 64-lane wave per batch row, but pos and neg
// triples are processed in two sequential phases (#pragma unroll 1 loop)
// so only 6 float4 gathers are live at once -> VGPR <= 64 -> 8 waves/SIMD
// (full 32 waves/CU residency for the 8192-wave grid).
__global__ __launch_bounds__(256, 8) void transd_kernel(
    const int* __restrict__ X, const int* __restrict__ Y,
    const float* __restrict__ ent_emb, const float* __restrict__ rel_emb,
    const float* __restrict__ ent_proj, const float* __restrict__ rel_proj,
    float* __restrict__ out)
{
    const int gtid = blockIdx.x * blockDim.x + threadIdx.x;
    const int b    = gtid >> 6;
    const int lane = gtid & 63;
    if (b >= kB) return;

    float lossP = 0.0f, lossN = 0.0f;

    #pragma unroll 1
    for (int s = 0; s < 2; ++s) {
        const int* __restrict__ T = (s == 0) ? X : Y;
        const int ih = T[b * 3 + 0], ir = T[b * 3 + 1], it = T[b * 3 + 2];

        // 6 coalesced 1KB row-gathers, all issued before any use.
        float4 h  = ld4(ent_emb,  ih, lane);
        float4 r  = ld4(rel_emb,  ir, lane);
        float4 t  = ld4(ent_emb,  it, lane);
        float4 hp = ld4(ent_proj, ih, lane);
        float4 rp = ld4(rel_proj, ir, lane);
        float4 tp = ld4(ent_proj, it, lane);

        // projection dots: dot(h_p, h), dot(t_p, t)
        float dh = dot4(hp, h);
        float dt = dot4(tp, t);
        #pragma unroll
        for (int off = 1; off < 64; off <<= 1) {
            dh += __shfl_xor(dh, off, 64);
            dt += __shfl_xor(dt, off, 64);
        }

        // h_ = h + r_p * dh; t_ = t + r_p * dt
        float4 h_ = fma4(h, rp, dh);
        float4 t_ = fma4(t, rp, dt);

        // squared norms of h_, r, t_
        float qh = dot4(h_, h_);
        float qr = dot4(r, r);
        float qt = dot4(t_, t_);
        #pragma unroll
        for (int off = 1; off < 64; off <<= 1) {
            qh += __shfl_xor(qh, off, 64);
            qr += __shfl_xor(qr, off, 64);
            qt += __shfl_xor(qt, off, 64);
        }

        const float inh = 1.0f / fmaxf(sqrtf(qh), kEps);
        const float inr = 1.0f / fmaxf(sqrtf(qr), kEps);
        const float int_ = 1.0f / fmaxf(sqrtf(qt), kEps);

        // s = normalize(h_) + normalize(r) - normalize(t_)
        float4 sv;
        sv.x = h_.x * inh + r.x * inr - t_.x * int_;
        sv.y = h_.y * inh + r.y * inr - t_.y * int_;
        sv.z = h_.z * inh + r.z * inr - t_.z * int_;
        sv.w = h_.w * inh + r.w * inr - t_.w * int_;

        float ss = dot4(sv, sv);
        #pragma unroll
        for (int off = 1; off < 64; off <<= 1) {
            ss += __shfl_xor(ss, off, 64);
        }

        const float l = sqrtf(ss);
        if (s == 0) lossP = l; else lossN = l;
    }

    if (lane == 0) {
        out[b] = fmaxf(lossP - lossN + kMargin, 0.0f);
    }
}

} // namespace

extern "C" void kernel_launch(void* const* d_in, const int* in_sizes, int n_in,
                              void* d_out, int out_size, void* d_ws, size_t ws_size,
                              hipStream_t stream) {
    const int*   X        = (const int*)  d_in[0];
    const int*   Y        = (const int*)  d_in[1];
    const float* ent_emb  = (const float*)d_in[2];
    const float* rel_emb  = (const float*)d_in[3];
    const float* ent_proj = (const float*)d_in[4];
    const float* rel_proj = (const float*)d_in[5];
    float*       out      = (float*)d_out;

    // one 64-lane wave per batch row; 4 waves per 256-thread block
    const int threads = 256;
    const int blocks  = (kB * 64) / threads;   // 2048
    transd_kernel<<<blocks, threads, 0, stream>>>(
        X, Y, ent_emb, rel_emb, ent_proj, rel_proj, out);
}

// Round 6
// 21.321 us; speedup vs baseline: 1.0366x; 1.0124x over previous
//
#include <hip/hip_runtime.h>
#include <math.h>

namespace {

constexpr int   kB      = 8192;
constexpr int   kD      = 256;      // dims; 64 lanes * float4
constexpr float kMargin = 1.0f;
constexpr float kEps    = 1e-12f;

__device__ inline float4 ld4(const float* __restrict__ tab, int row, int lane) {
    return reinterpret_cast<const float4*>(tab + (size_t)row * kD)[lane];
}

__device__ inline float dot4(const float4& a, const float4& b) {
    return a.x * b.x + a.y * b.y + a.z * b.z + a.w * b.w;
}

// a + b * s
__device__ inline float4 fma4(const float4& a, const float4& b, float s) {
    float4 r;
    r.x = fmaf(b.x, s, a.x);
    r.y = fmaf(b.y, s, a.y);
    r.z = fmaf(b.z, s, a.z);
    r.w = fmaf(b.w, s, a.w);
    return r;
}

// One wave per (row, phase): pos and neg triples of a row run CONCURRENTLY
// in sibling waves of the same block (instead of serial phases), halving the
// per-wave dependency chain and doubling the number of schedulable work
// quanta (16384 waves) to smooth the straggler tail. Scalar losses meet in
// 32 B of LDS.
__global__ __launch_bounds__(256, 8) void transd_kernel(
    const int* __restrict__ X, const int* __restrict__ Y,
    const float* __restrict__ ent_emb, const float* __restrict__ rel_emb,
    const float* __restrict__ ent_proj, const float* __restrict__ rel_proj,
    float* __restrict__ out)
{
    __shared__ float ls[2][2];   // [row_in_block][phase]

    const int tid  = threadIdx.x;
    const int wid  = tid >> 6;         // 0..3
    const int lane = tid & 63;
    const int rin  = wid >> 1;         // row within block: 0,1
    const int ph   = wid & 1;          // 0 = pos(X), 1 = neg(Y)
    const int b    = blockIdx.x * 2 + rin;

    const int* __restrict__ T = ph ? Y : X;
    const int ih = T[b * 3 + 0], ir = T[b * 3 + 1], it = T[b * 3 + 2];

    // 6 coalesced 1KB row-gathers, all issued before any use.
    float4 h  = ld4(ent_emb,  ih, lane);
    float4 r  = ld4(rel_emb,  ir, lane);
    float4 t  = ld4(ent_emb,  it, lane);
    float4 hp = ld4(ent_proj, ih, lane);
    float4 rp = ld4(rel_proj, ir, lane);
    float4 tp = ld4(ent_proj, it, lane);

    // projection dots: dot(h_p, h), dot(t_p, t)
    float dh = dot4(hp, h);
    float dt = dot4(tp, t);
    #pragma unroll
    for (int off = 1; off < 64; off <<= 1) {
        dh += __shfl_xor(dh, off, 64);
        dt += __shfl_xor(dt, off, 64);
    }

    // h_ = h + r_p * dh; t_ = t + r_p * dt
    float4 h_ = fma4(h, rp, dh);
    float4 t_ = fma4(t, rp, dt);

    // squared norms of h_, r, t_
    float qh = dot4(h_, h_);
    float qr = dot4(r, r);
    float qt = dot4(t_, t_);
    #pragma unroll
    for (int off = 1; off < 64; off <<= 1) {
        qh += __shfl_xor(qh, off, 64);
        qr += __shfl_xor(qr, off, 64);
        qt += __shfl_xor(qt, off, 64);
    }

    const float inh = 1.0f / fmaxf(sqrtf(qh), kEps);
    const float inr = 1.0f / fmaxf(sqrtf(qr), kEps);
    const float int_ = 1.0f / fmaxf(sqrtf(qt), kEps);

    // s = normalize(h_) + normalize(r) - normalize(t_)
    float4 sv;
    sv.x = h_.x * inh + r.x * inr - t_.x * int_;
    sv.y = h_.y * inh + r.y * inr - t_.y * int_;
    sv.z = h_.z * inh + r.z * inr - t_.z * int_;
    sv.w = h_.w * inh + r.w * inr - t_.w * int_;

    float ss = dot4(sv, sv);
    #pragma unroll
    for (int off = 1; off < 64; off <<= 1) {
        ss += __shfl_xor(ss, off, 64);
    }

    if (lane == 0) ls[rin][ph] = sqrtf(ss);
    __syncthreads();

    if (ph == 0 && lane == 0) {
        out[b] = fmaxf(ls[rin][0] - ls[rin][1] + kMargin, 0.0f);
    }
}

} // namespace

extern "C" void kernel_launch(void* const* d_in, const int* in_sizes, int n_in,
                              void* d_out, int out_size, void* d_ws, size_t ws_size,
                              hipStream_t stream) {
    const int*   X        = (const int*)  d_in[0];
    const int*   Y        = (const int*)  d_in[1];
    const float* ent_emb  = (const float*)d_in[2];
    const float* rel_emb  = (const float*)d_in[3];
    const float* ent_proj = (const float*)d_in[4];
    const float* rel_proj = (const float*)d_in[5];
    float*       out      = (float*)d_out;

    // 2 rows per 256-thread block: waves (pos,neg) x 2 rows
    const int threads = 256;
    const int blocks  = kB / 2;   // 4096
    transd_kernel<<<blocks, threads, 0, stream>>>(
        X, Y, ent_emb, rel_emb, ent_proj, rel_proj, out);
}

// Round 9
// 20.362 us; speedup vs baseline: 1.0855x; 1.0471x over previous
//
#include <hip/hip_runtime.h>
#include <math.h>

namespace {

constexpr int   kB      = 8192;
constexpr int   kD      = 256;      // dims; 64 lanes * float4
constexpr float kMargin = 1.0f;
constexpr float kEps    = 1e-12f;

typedef float f32x4 __attribute__((ext_vector_type(4)));

// Non-temporal row-gather: the tables (410 MB, random access, ~8% reuse)
// thrash L1/L2 -- mark loads streaming / early-evict.
// __builtin_nontemporal_load needs a native/ext-vector pointer, not
// HIP_vector_type<float,4>*.
__device__ inline float4 ld4nt(const float* __restrict__ tab, int row, int lane) {
    const f32x4* p = reinterpret_cast<const f32x4*>(tab + (size_t)row * kD) + lane;
    f32x4 v = __builtin_nontemporal_load(p);
    return make_float4(v.x, v.y, v.z, v.w);
}

__device__ inline float dot4(const float4& a, const float4& b) {
    return a.x * b.x + a.y * b.y + a.z * b.z + a.w * b.w;
}

// a + b * s
__device__ inline float4 fma4(const float4& a, const float4& b, float s) {
    float4 r;
    r.x = fmaf(b.x, s, a.x);
    r.y = fmaf(b.y, s, a.y);
    r.z = fmaf(b.z, s, a.z);
    r.w = fmaf(b.w, s, a.w);
    return r;
}

// One wave per (row, phase): pos and neg triples of a row run concurrently
// in sibling waves of the same block; scalar losses meet in LDS.
__global__ __launch_bounds__(256, 8) void transd_kernel(
    const int* __restrict__ X, const int* __restrict__ Y,
    const float* __restrict__ ent_emb, const float* __restrict__ rel_emb,
    const float* __restrict__ ent_proj, const float* __restrict__ rel_proj,
    float* __restrict__ out)
{
    __shared__ float ls[2][2];   // [row_in_block][phase]

    const int tid  = threadIdx.x;
    const int wid  = tid >> 6;         // 0..3
    const int lane = tid & 63;
    const int rin  = wid >> 1;         // row within block: 0,1
    const int ph   = wid & 1;          // 0 = pos(X), 1 = neg(Y)
    const int b    = blockIdx.x * 2 + rin;

    const int* __restrict__ T = ph ? Y : X;
    const int ih = T[b * 3 + 0], ir = T[b * 3 + 1], it = T[b * 3 + 2];

    // 6 coalesced 1KB row-gathers, all issued before any use.
    float4 h  = ld4nt(ent_emb,  ih, lane);
    float4 r  = ld4nt(rel_emb,  ir, lane);
    float4 t  = ld4nt(ent_emb,  it, lane);
    float4 hp = ld4nt(ent_proj, ih, lane);
    float4 rp = ld4nt(rel_proj, ir, lane);
    float4 tp = ld4nt(ent_proj, it, lane);

    // projection dots: dot(h_p, h), dot(t_p, t)
    float dh = dot4(hp, h);
    float dt = dot4(tp, t);
    #pragma unroll
    for (int off = 1; off < 64; off <<= 1) {
        dh += __shfl_xor(dh, off, 64);
        dt += __shfl_xor(dt, off, 64);
    }

    // h_ = h + r_p * dh; t_ = t + r_p * dt
    float4 h_ = fma4(h, rp, dh);
    float4 t_ = fma4(t, rp, dt);

    // squared norms of h_, r, t_
    float qh = dot4(h_, h_);
    float qr = dot4(r, r);
    float qt = dot4(t_, t_);
    #pragma unroll
    for (int off = 1; off < 64; off <<= 1) {
        qh += __shfl_xor(qh, off, 64);
        qr += __shfl_xor(qr, off, 64);
        qt += __shfl_xor(qt, off, 64);
    }

    const float inh = 1.0f / fmaxf(sqrtf(qh), kEps);
    const float inr = 1.0f / fmaxf(sqrtf(qr), kEps);
    const float int_ = 1.0f / fmaxf(sqrtf(qt), kEps);

    // s = normalize(h_) + normalize(r) - normalize(t_)
    float4 sv;
    sv.x = h_.x * inh + r.x * inr - t_.x * int_;
    sv.y = h_.y * inh + r.y * inr - t_.y * int_;
    sv.z = h_.z * inh + r.z * inr - t_.z * int_;
    sv.w = h_.w * inh + r.w * inr - t_.w * int_;

    float ss = dot4(sv, sv);
    #pragma unroll
    for (int off = 1; off < 64; off <<= 1) {
        ss += __shfl_xor(ss, off, 64);
    }

    if (lane == 0) ls[rin][ph] = sqrtf(ss);
    __syncthreads();

    if (ph == 0 && lane == 0) {
        out[b] = fmaxf(ls[rin][0] - ls[rin][1] + kMargin, 0.0f);
    }
}

} // namespace

extern "C" void kernel_launch(void* const* d_in, const int* in_sizes, int n_in,
                              void* d_out, int out_size, void* d_ws, size_t ws_size,
                              hipStream_t stream) {
    const int*   X        = (const int*)  d_in[0];
    const int*   Y        = (const int*)  d_in[1];
    const float* ent_emb  = (const float*)d_in[2];
    const float* rel_emb  = (const float*)d_in[3];
    const float* ent_proj = (const float*)d_in[4];
    const float* rel_proj = (const float*)d_in[5];
    float*       out      = (float*)d_out;

    // 2 rows per 256-thread block: waves (pos,neg) x 2 rows
    const int threads = 256;
    const int blocks  = kB / 2;   // 4096
    transd_kernel<<<blocks, threads, 0, stream>>>(
        X, Y, ent_emb, rel_emb, ent_proj, rel_proj, out);
}